// Round 8
// baseline (155.950 us; speedup 1.0000x reference)
//
#include <hip/hip_runtime.h>

// QuantizedBKCore: tridiagonal resolvent diagonal via two continued-fraction
// sweeps, bit-exact vs numpy float32/complex64 reference (validated R1-R7:
// absmax == 0 with Smith division, contract(off), rintf, exact op order).
//
// R8: R7 = 68us, VALUBusy 62%, per-wave duty ~26%: the serial carry chain
// (two dependent IEEE f32 div expansions/step, ~400-600cyc latency vs
// ~150cyc issue) stalls each wave and effective occupancy is only ~2.4
// waves/SIMD. Fix = ILP: TWO independent chains per lane (segments tid and
// tid+64 of a 128-segment chunk) so chain B's issue fills chain A's stalls
// inside one wave. Also WARM 32->24 (-10% work): data is quantized, slowest
// site a=0 contracts 0.382/step -> gap 0.7*0.382^24 ~ 6e-11 ~ 0.002 ulp ->
// certain bit-merge. Rr/Ri scratch spill stays (R7: cache-contained,
// WRITE == output only). cc via zero-padded d_ws copy + aligned float4.

#define SEG   32                  // elements per chain-segment
#define WARM  24                  // warmup steps (worst realistic gap ~6e-11)
#define LANES 64                  // threads per block (1 wave)
#define NSEG  128                 // segments per chunk (2 per lane)
#define CHUNK (NSEG*SEG)          // 4096 elements per block
#define HALO  WARM                // multiple of 4: float4 alignment math holds
#define STAGE (CHUNK + 2*HALO)    // 4144 staged negA values
#define SPAD  (STAGE + STAGE/32 + 1)  // stride-33 padding (2-way only: free)

struct C2 { float r, i; };

__device__ __forceinline__ int padi(int i) { return i + (i >> 5); }

// numpy CFLOAT_divide (Smith), numerator (nr, 0), no FMA contraction.
__device__ __forceinline__ C2 npdiv(float nr, float dr, float di) {
  #pragma clang fp contract(off)
  const bool  b   = fabsf(dr) >= fabsf(di);
  const float num = b ? di : dr;
  const float den = b ? dr : di;
  const float rat = num / den;          // IEEE-correct div
  const float t   = num * rat;
  const float s   = den + t;            // mul + add, NOT fma
  const float scl = 1.0f / s;           // IEEE-correct div
  const float u   = nr * scl;
  const float m   = nr * rat;
  const float w   = m * scl;
  C2 o;
  o.r = b ? u : w;
  o.i = b ? -w : -u;                    // sign-of-product flip is exact
  return o;
}

// one continued-fraction step: carry <- cv / (z - a - carry), z = i
__device__ __forceinline__ void cf_step(float na, float cv, float& cr, float& ci) {
  #pragma clang fp contract(off)
  const float dr = na - cr;
  const float di = 1.0f - ci;
  const C2 nc = npdiv(cv, dr, di);
  cr = nc.r; ci = nc.i;
}

// -(clip(h0_diag + fake_quantize(v), -10, 10)); exact op order.
__device__ __forceinline__ float neg_a(float vv, float hd) {
  #pragma clang fp contract(off)
  float q = rintf(vv);                  // round half-even == np.rint
  q = fminf(fmaxf(q, -128.0f), 127.0f);
  float he = hd + q;
  he = fminf(fmaxf(he, -10.0f), 10.0f);
  return 0.0f - he;                     // Re(z - a)
}

// clip(+-100) -> rint -> clip(+-128); exact ops.
__device__ __forceinline__ float fq_out(float x) {
  #pragma clang fp contract(off)
  x = fminf(fmaxf(x, -100.0f), 100.0f);
  x = rintf(x);
  x = fminf(fmaxf(x, -128.0f), 127.0f);
  return x;
}

// ccf[i] = cc[i-HALO] zero-padded: i in [0, N + 2*HALO + 8)
__global__ void cc_kernel(const float* __restrict__ hsub,
                          const float* __restrict__ hsup,
                          float* __restrict__ ccf, int N) {
  #pragma clang fp contract(off)
  const int i = blockIdx.x * blockDim.x + threadIdx.x;
  if (i < N + 2*HALO + 8) {
    const int k = i - HALO;
    ccf[i] = (k >= 0 && k < N - 1) ? hsub[k] * hsup[k] : 0.0f;
  }
}

// w[0..7] = cc[m0..m0+7], where (m0+HALO) % 4 == 0: two aligned float4 loads.
__device__ __forceinline__ void load8_f(const float4* __restrict__ cc4,
                                        int m0, float* w) {
  const int q = (m0 + HALO) >> 2;
  const float4 A = cc4[q];
  const float4 B = cc4[q + 1];
  w[0]=A.x; w[1]=A.y; w[2]=A.z; w[3]=A.w;
  w[4]=B.x; w[5]=B.y; w[6]=B.z; w[7]=B.w;
}

// w[0..7] = cc[m0..m0+7], where (m0+HALO) % 4 == 3: three aligned float4 loads.
__device__ __forceinline__ void load8_b(const float4* __restrict__ cc4,
                                        int m0, float* w) {
  const int q = (m0 + HALO - 3) >> 2;   // (m0+HALO-3) % 4 == 0
  const float4 A = cc4[q];              // covers m0-3 .. m0
  const float4 B = cc4[q + 1];          // m0+1 .. m0+4
  const float4 C = cc4[q + 2];          // m0+5 .. m0+8
  w[0]=A.w;
  w[1]=B.x; w[2]=B.y; w[3]=B.z; w[4]=B.w;
  w[5]=C.x; w[6]=C.y; w[7]=C.z;
}

__global__ void __launch_bounds__(LANES, 4)   // VGPR cap 128
bk_kernel(const float* __restrict__ v,
          const float* __restrict__ hdiag,
          const float* __restrict__ ccf,      // zero-padded couplings (d_ws)
          float2* __restrict__ out,
          int N, int chunks_per_row) {
  #pragma clang fp contract(off)
  __shared__ float sA[SPAD];            // negA only: ~17.1 KB

  const int tid  = threadIdx.x;
  const int row  = blockIdx.x / chunks_per_row;
  const int ch   = blockIdx.x - row * chunks_per_row;
  const int base = ch * CHUNK;
  const long rowoff = (long)row * N;
  const float4* cc4 = (const float4*)ccf;

  // ---- stage negA, coalesced; zeros outside [0,N) --------------------------
  for (int i = tid; i < STAGE; i += LANES) {
    const int k = base - HALO + i;
    float na = 0.0f;
    if (k >= 0 && k < N) na = neg_a(v[rowoff + k], hdiag[k]);
    sA[padi(i)] = na;
  }
  __syncthreads();

  // chain A: segment tid; chain B: segment tid+64 (independent ILP pair)
  const int s0A = base + tid * SEG;
  const int s0B = s0A + 64 * SEG;
  const int s1A = s0A + SEG;
  const int s1B = s0B + SEG;
  const int liA = tid * SEG + HALO;           // sA (unpadded) index of s0A
  const int liB = liA + 64 * SEG;

  float RrA[SEG], RiA[SEG], RrB[SEG], RiB[SEG];
  float crA, ciA, crB, ciB;
  float wcA[8], wcB[8];

  // ---- backward warmup: k = s1+WARM-1 .. s1, carry from 0 -----------------
  // R[k-1] = cc[k-1] / (z - a[k] - R[k]); zero-padded fakes are transparent.
  crA = 0.0f; ciA = 0.0f; crB = 0.0f; ciB = 0.0f;
  for (int g = 0; g < WARM / 8; ++g) {
    const int khA = s1A + (WARM - 1) - 8 * g; // high k of this group
    const int khB = s1B + (WARM - 1) - 8 * g;
    load8_b(cc4, khA - 8, wcA);               // wc[j'] = cc[kh-8+j']
    load8_b(cc4, khB - 8, wcB);
    #pragma unroll
    for (int j = 0; j < 8; ++j) {             // k = kh - j
      const float naA = sA[padi(khA - j - base + HALO)];
      const float naB = sA[padi(khB - j - base + HALO)];
      cf_step(naA, wcA[7 - j], crA, ciA);     // cc[k-1]
      cf_step(naB, wcB[7 - j], crB, ciB);
    }
  }
  RrA[SEG-1] = crA; RiA[SEG-1] = ciA;         // R[s1-1]
  RrB[SEG-1] = crB; RiB[SEG-1] = ciB;

  // ---- backward main: t = SEG-1 .. 1, store R -----------------------------
  #pragma unroll
  for (int tg = 0; tg < SEG / 8; ++tg) {
    const int th = SEG - 1 - 8 * tg;          // high t of this group
    load8_b(cc4, s0A + th - 8, wcA);          // wc[j'] = cc[s0+th-8+j']
    load8_b(cc4, s0B + th - 8, wcB);
    #pragma unroll
    for (int j = 0; j < 8; ++j) {
      const int t = th - j;
      if (t >= 1) {
        const float naA = sA[padi(liA + t)];
        const float naB = sA[padi(liB + t)];
        cf_step(naA, wcA[7 - j], crA, ciA);   // cc[k-1], k = s0+t
        cf_step(naB, wcB[7 - j], crB, ciB);
        RrA[t-1] = crA; RiA[t-1] = ciA;
        RrB[t-1] = crB; RiB[t-1] = ciB;
      }
    }
  }

  // ---- forward warmup: k = s0-WARM .. s0-1, carry from 0 ------------------
  // L[k+1] = cc[k] / (z - a[k] - L[k])
  crA = 0.0f; ciA = 0.0f; crB = 0.0f; ciB = 0.0f;
  for (int g = 0; g < WARM / 8; ++g) {
    const int klA = s0A - WARM + 8 * g;       // low k of this group
    const int klB = s0B - WARM + 8 * g;
    load8_f(cc4, klA, wcA);                   // wc[j] = cc[kl+j]
    load8_f(cc4, klB, wcB);
    #pragma unroll
    for (int j = 0; j < 8; ++j) {
      const float naA = sA[padi(klA + j - base + HALO)];
      const float naB = sA[padi(klB + j - base + HALO)];
      cf_step(naA, wcA[j], crA, ciA);
      cf_step(naB, wcB[j], crB, ciB);
    }
  }

  // ---- forward main: combine with R, store G, advance L -------------------
  #pragma unroll
  for (int tg = 0; tg < SEG / 8; ++tg) {
    const int klA = s0A + 8 * tg;
    const int klB = s0B + 8 * tg;
    load8_f(cc4, klA, wcA);                   // wc[j] = cc[kl+j]
    load8_f(cc4, klB, wcB);
    #pragma unroll
    for (int j = 0; j < 8; ++j) {
      const int t = 8 * tg + j;
      { // chain A
        const float na  = sA[padi(liA + t)];
        const float drL = na - crA;           // (z - a) - L
        const float diL = 1.0f - ciA;
        const float drf = drL - RrA[t];       // ... - R
        const float dif = diL - RiA[t];
        const C2 G = npdiv(1.0f, drf, dif);
        out[rowoff + klA + j] = make_float2(fq_out(G.r), fq_out(G.i));
        if (t < SEG - 1) {                    // advance L within segment
          const C2 nc = npdiv(wcA[j], drL, diL);
          crA = nc.r; ciA = nc.i;
        }
      }
      { // chain B
        const float na  = sA[padi(liB + t)];
        const float drL = na - crB;
        const float diL = 1.0f - ciB;
        const float drf = drL - RrB[t];
        const float dif = diL - RiB[t];
        const C2 G = npdiv(1.0f, drf, dif);
        out[rowoff + klB + j] = make_float2(fq_out(G.r), fq_out(G.i));
        if (t < SEG - 1) {
          const C2 nc = npdiv(wcB[j], drL, diL);
          crB = nc.r; ciB = nc.i;
        }
      }
    }
  }
}

extern "C" void kernel_launch(void* const* d_in, const int* in_sizes, int n_in,
                              void* d_out, int out_size, void* d_ws, size_t ws_size,
                              hipStream_t stream) {
  const float* v    = (const float*)d_in[0];
  const float* hd   = (const float*)d_in[1];
  const float* hsub = (const float*)d_in[2];
  const float* hsup = (const float*)d_in[3];
  const int N = in_sizes[1];
  const int B = in_sizes[0] / N;
  const int chunks = (N + CHUNK - 1) / CHUNK;    // 4 for N=16384 (exact)

  float* ccf = (float*)d_ws;                     // N + 2*HALO + 8 floats
  const int ccn = N + 2*HALO + 8;
  cc_kernel<<<(ccn + 255) / 256, 256, 0, stream>>>(hsub, hsup, ccf, N);
  bk_kernel<<<B * chunks, LANES, 0, stream>>>(v, hd, ccf, (float2*)d_out,
                                              N, chunks);
}

// Round 9
// 140.412 us; speedup vs baseline: 1.1107x; 1.1107x over previous
//
#include <hip/hip_runtime.h>

// QuantizedBKCore: tridiagonal resolvent diagonal via two continued-fraction
// sweeps, bit-exact vs numpy float32/complex64 reference (validated R1-R8:
// absmax == 0 with Smith division, contract(off), rintf, exact op order).
//
// R9 = R7 shape (CHUNK 2048 / LANES 64 / LDS 8.7KB / cache-contained R spill,
// 68us @ VALUBusy 62%) + free ILP: the forward WARMUP is independent of the
// whole backward sweep (both start from carry=0), so it is interleaved with
// the backward warmup pairwise — serial chain 110 -> 86 steps and 2x issue
// during the paired phase, at ~+25 VGPR and no new arrays. R8 showed state-
// heavy ILP (2 full chains/lane) halves occupancy and leaks spill to HBM
// (WRITE 65->140MB) — rejected. WARM=24 validated in R8 (absmax 0).
// cc via zero-padded d_ws copy + aligned float4 group loads (R6).

#define SEG   32                  // elements per lane
#define WARM  24                  // warmup steps (worst realistic gap ~6e-11)
#define LANES 64                  // threads per block (1 wave)
#define CHUNK (LANES*SEG)         // 2048 elements per block
#define HALO  WARM                // multiple of 4: float4 alignment math holds
#define STAGE (CHUNK + 2*HALO)    // 2096 staged negA values
#define SPAD  (STAGE + STAGE/32 + 1)  // stride-33 padding (2-way only: free)

struct C2 { float r, i; };

__device__ __forceinline__ int padi(int i) { return i + (i >> 5); }

// numpy CFLOAT_divide (Smith), numerator (nr, 0), no FMA contraction.
__device__ __forceinline__ C2 npdiv(float nr, float dr, float di) {
  #pragma clang fp contract(off)
  const bool  b   = fabsf(dr) >= fabsf(di);
  const float num = b ? di : dr;
  const float den = b ? dr : di;
  const float rat = num / den;          // IEEE-correct div
  const float t   = num * rat;
  const float s   = den + t;            // mul + add, NOT fma
  const float scl = 1.0f / s;           // IEEE-correct div
  const float u   = nr * scl;
  const float m   = nr * rat;
  const float w   = m * scl;
  C2 o;
  o.r = b ? u : w;
  o.i = b ? -w : -u;                    // sign-of-product flip is exact
  return o;
}

// one continued-fraction step: carry <- cv / (z - a - carry), z = i
__device__ __forceinline__ void cf_step(float na, float cv, float& cr, float& ci) {
  #pragma clang fp contract(off)
  const float dr = na - cr;
  const float di = 1.0f - ci;
  const C2 nc = npdiv(cv, dr, di);
  cr = nc.r; ci = nc.i;
}

// -(clip(h0_diag + fake_quantize(v), -10, 10)); exact op order.
__device__ __forceinline__ float neg_a(float vv, float hd) {
  #pragma clang fp contract(off)
  float q = rintf(vv);                  // round half-even == np.rint
  q = fminf(fmaxf(q, -128.0f), 127.0f);
  float he = hd + q;
  he = fminf(fmaxf(he, -10.0f), 10.0f);
  return 0.0f - he;                     // Re(z - a)
}

// clip(+-100) -> rint -> clip(+-128); exact ops.
__device__ __forceinline__ float fq_out(float x) {
  #pragma clang fp contract(off)
  x = fminf(fmaxf(x, -100.0f), 100.0f);
  x = rintf(x);
  x = fminf(fmaxf(x, -128.0f), 127.0f);
  return x;
}

// ccf[i] = cc[i-HALO] zero-padded: i in [0, N + 2*HALO + 8)
__global__ void cc_kernel(const float* __restrict__ hsub,
                          const float* __restrict__ hsup,
                          float* __restrict__ ccf, int N) {
  #pragma clang fp contract(off)
  const int i = blockIdx.x * blockDim.x + threadIdx.x;
  if (i < N + 2*HALO + 8) {
    const int k = i - HALO;
    ccf[i] = (k >= 0 && k < N - 1) ? hsub[k] * hsup[k] : 0.0f;
  }
}

// w[0..7] = cc[m0..m0+7], where (m0+HALO) % 4 == 0: two aligned float4 loads.
__device__ __forceinline__ void load8_f(const float4* __restrict__ cc4,
                                        int m0, float* w) {
  const int q = (m0 + HALO) >> 2;
  const float4 A = cc4[q];
  const float4 B = cc4[q + 1];
  w[0]=A.x; w[1]=A.y; w[2]=A.z; w[3]=A.w;
  w[4]=B.x; w[5]=B.y; w[6]=B.z; w[7]=B.w;
}

// w[0..7] = cc[m0..m0+7], where (m0+HALO) % 4 == 3: three aligned float4 loads.
__device__ __forceinline__ void load8_b(const float4* __restrict__ cc4,
                                        int m0, float* w) {
  const int q = (m0 + HALO - 3) >> 2;   // (m0+HALO-3) % 4 == 0
  const float4 A = cc4[q];              // covers m0-3 .. m0
  const float4 B = cc4[q + 1];          // m0+1 .. m0+4
  const float4 C = cc4[q + 2];          // m0+5 .. m0+8
  w[0]=A.w;
  w[1]=B.x; w[2]=B.y; w[3]=B.z; w[4]=B.w;
  w[5]=C.x; w[6]=C.y; w[7]=C.z;
}

__global__ void __launch_bounds__(LANES, 4)   // VGPR cap 128
bk_kernel(const float* __restrict__ v,
          const float* __restrict__ hdiag,
          const float* __restrict__ ccf,      // zero-padded couplings (d_ws)
          float2* __restrict__ out,
          int N, int chunks_per_row) {
  #pragma clang fp contract(off)
  __shared__ float sA[SPAD];            // negA only: ~8.7 KB

  const int tid  = threadIdx.x;
  const int row  = blockIdx.x / chunks_per_row;
  const int ch   = blockIdx.x - row * chunks_per_row;
  const int base = ch * CHUNK;
  const long rowoff = (long)row * N;
  const float4* cc4 = (const float4*)ccf;

  // ---- stage negA, coalesced; zeros outside [0,N) --------------------------
  for (int i = tid; i < STAGE; i += LANES) {
    const int k = base - HALO + i;
    float na = 0.0f;
    if (k >= 0 && k < N) na = neg_a(v[rowoff + k], hdiag[k]);
    sA[padi(i)] = na;
  }
  __syncthreads();

  const int s0  = base + tid * SEG;
  const int s1  = s0 + SEG;
  const int li0 = tid * SEG + HALO;     // sA (unpadded) index of s0

  float Rr[SEG], Ri[SEG];               // spills to scratch; L2-contained (R7)
  float crB, ciB;                       // backward carry (R)
  float crF, ciF;                       // forward-warmup carry (L)
  float wcB[8], wcF[8];

  // ---- paired warmups (independent chains, interleaved for ILP) -----------
  // bwd: R[k-1] = cc[k-1] / (z - a[k] - R[k]), k = s1+WARM-1 .. s1, carry 0.
  // fwd: L[k+1] = cc[k]   / (z - a[k] - L[k]), k = s0-WARM .. s0-1, carry 0.
  // Zero-padded fake steps (cc=0) are bit-transparent (validated R4+).
  crB = 0.0f; ciB = 0.0f; crF = 0.0f; ciF = 0.0f;
  for (int g = 0; g < WARM / 8; ++g) {
    const int kh = s1 + (WARM - 1) - 8 * g;   // bwd group high k
    const int kl = s0 - WARM + 8 * g;         // fwd group low k
    load8_b(cc4, kh - 8, wcB);                // wcB[j'] = cc[kh-8+j']
    load8_f(cc4, kl, wcF);                    // wcF[j]  = cc[kl+j]
    #pragma unroll
    for (int j = 0; j < 8; ++j) {
      const float naB = sA[padi(kh - j - base + HALO)];
      const float naF = sA[padi(kl + j - base + HALO)];
      cf_step(naB, wcB[7 - j], crB, ciB);     // cc[k-1], k = kh-j
      cf_step(naF, wcF[j],     crF, ciF);     // cc[k],   k = kl+j
    }
  }
  Rr[SEG-1] = crB; Ri[SEG-1] = ciB;           // R[s1-1]

  // ---- backward main: t = SEG-1 .. 1, store R -----------------------------
  #pragma unroll
  for (int tg = 0; tg < SEG / 8; ++tg) {
    const int th = SEG - 1 - 8 * tg;          // high t of this group
    load8_b(cc4, s0 + th - 8, wcB);           // wcB[j'] = cc[s0+th-8+j']
    #pragma unroll
    for (int j = 0; j < 8; ++j) {
      const int t = th - j;
      if (t >= 1) {
        const float na = sA[padi(li0 + t)];
        cf_step(na, wcB[7 - j], crB, ciB);    // cc[k-1], k = s0+t
        Rr[t-1] = crB; Ri[t-1] = ciB;
      }
    }
  }

  // ---- forward main: combine with R, store G, advance L -------------------
  // (combine-npdiv and advance-npdiv are mutually independent: 2-wide ILP)
  #pragma unroll
  for (int tg = 0; tg < SEG / 8; ++tg) {
    const int kl = s0 + 8 * tg;
    load8_f(cc4, kl, wcF);                    // wcF[j] = cc[kl+j]
    #pragma unroll
    for (int j = 0; j < 8; ++j) {
      const int t = 8 * tg + j;
      const float na  = sA[padi(li0 + t)];
      const float drL = na - crF;             // (z - a) - L
      const float diL = 1.0f - ciF;
      const float drf = drL - Rr[t];          // ... - R
      const float dif = diL - Ri[t];
      const C2 G = npdiv(1.0f, drf, dif);
      out[rowoff + kl + j] = make_float2(fq_out(G.r), fq_out(G.i));
      if (t < SEG - 1) {                      // advance L within segment
        const C2 nc = npdiv(wcF[j], drL, diL);
        crF = nc.r; ciF = nc.i;
      }
    }
  }
}

extern "C" void kernel_launch(void* const* d_in, const int* in_sizes, int n_in,
                              void* d_out, int out_size, void* d_ws, size_t ws_size,
                              hipStream_t stream) {
  const float* v    = (const float*)d_in[0];
  const float* hd   = (const float*)d_in[1];
  const float* hsub = (const float*)d_in[2];
  const float* hsup = (const float*)d_in[3];
  const int N = in_sizes[1];
  const int B = in_sizes[0] / N;
  const int chunks = (N + CHUNK - 1) / CHUNK;    // 8 for N=16384 (exact)

  float* ccf = (float*)d_ws;                     // N + 2*HALO + 8 floats
  const int ccn = N + 2*HALO + 8;
  cc_kernel<<<(ccn + 255) / 256, 256, 0, stream>>>(hsub, hsup, ccf, N);
  bk_kernel<<<B * chunks, LANES, 0, stream>>>(v, hd, ccf, (float2*)d_out,
                                              N, chunks);
}

// Round 10
// 140.407 us; speedup vs baseline: 1.1107x; 1.0000x over previous
//
#include <hip/hip_runtime.h>

// QuantizedBKCore: tridiagonal resolvent diagonal via two continued-fraction
// sweeps, bit-exact vs numpy float32/complex64 reference (validated R1-R9:
// absmax == 0 with Smith division, contract(off), rintf, exact op order).
//
// R10 = R9 + amdgpu_waves_per_eu(4,4). R9 evidence: VGPR_Count=56 with
// __launch_bounds__(64,4) — the 2nd arg is a waves/EU MINIMUM, so the
// allocator chased >4 waves/EU by spilling Rr/Ri to scratch; those scratch
// reloads sit in the fwd-main dependent path (L2 latency each combine) and
// cap VALUBusy at ~57%. Pinning min=max=4 gives a 128-VGPR budget with no
// incentive to spill: R stays in registers, 4 waves/SIMD, grid = 16
// blocks/CU matches residency exactly. Everything else identical to R9.

#define SEG   32                  // elements per lane
#define WARM  24                  // warmup steps (worst realistic gap ~6e-11)
#define LANES 64                  // threads per block (1 wave)
#define CHUNK (LANES*SEG)         // 2048 elements per block
#define HALO  WARM                // multiple of 4: float4 alignment math holds
#define STAGE (CHUNK + 2*HALO)    // 2096 staged negA values
#define SPAD  (STAGE + STAGE/32 + 1)  // stride-33 padding (2-way only: free)

struct C2 { float r, i; };

__device__ __forceinline__ int padi(int i) { return i + (i >> 5); }

// numpy CFLOAT_divide (Smith), numerator (nr, 0), no FMA contraction.
__device__ __forceinline__ C2 npdiv(float nr, float dr, float di) {
  #pragma clang fp contract(off)
  const bool  b   = fabsf(dr) >= fabsf(di);
  const float num = b ? di : dr;
  const float den = b ? dr : di;
  const float rat = num / den;          // IEEE-correct div
  const float t   = num * rat;
  const float s   = den + t;            // mul + add, NOT fma
  const float scl = 1.0f / s;           // IEEE-correct div
  const float u   = nr * scl;
  const float m   = nr * rat;
  const float w   = m * scl;
  C2 o;
  o.r = b ? u : w;
  o.i = b ? -w : -u;                    // sign-of-product flip is exact
  return o;
}

// one continued-fraction step: carry <- cv / (z - a - carry), z = i
__device__ __forceinline__ void cf_step(float na, float cv, float& cr, float& ci) {
  #pragma clang fp contract(off)
  const float dr = na - cr;
  const float di = 1.0f - ci;
  const C2 nc = npdiv(cv, dr, di);
  cr = nc.r; ci = nc.i;
}

// -(clip(h0_diag + fake_quantize(v), -10, 10)); exact op order.
__device__ __forceinline__ float neg_a(float vv, float hd) {
  #pragma clang fp contract(off)
  float q = rintf(vv);                  // round half-even == np.rint
  q = fminf(fmaxf(q, -128.0f), 127.0f);
  float he = hd + q;
  he = fminf(fmaxf(he, -10.0f), 10.0f);
  return 0.0f - he;                     // Re(z - a)
}

// clip(+-100) -> rint -> clip(+-128); exact ops.
__device__ __forceinline__ float fq_out(float x) {
  #pragma clang fp contract(off)
  x = fminf(fmaxf(x, -100.0f), 100.0f);
  x = rintf(x);
  x = fminf(fmaxf(x, -128.0f), 127.0f);
  return x;
}

// ccf[i] = cc[i-HALO] zero-padded: i in [0, N + 2*HALO + 8)
__global__ void cc_kernel(const float* __restrict__ hsub,
                          const float* __restrict__ hsup,
                          float* __restrict__ ccf, int N) {
  #pragma clang fp contract(off)
  const int i = blockIdx.x * blockDim.x + threadIdx.x;
  if (i < N + 2*HALO + 8) {
    const int k = i - HALO;
    ccf[i] = (k >= 0 && k < N - 1) ? hsub[k] * hsup[k] : 0.0f;
  }
}

// w[0..7] = cc[m0..m0+7], where (m0+HALO) % 4 == 0: two aligned float4 loads.
__device__ __forceinline__ void load8_f(const float4* __restrict__ cc4,
                                        int m0, float* w) {
  const int q = (m0 + HALO) >> 2;
  const float4 A = cc4[q];
  const float4 B = cc4[q + 1];
  w[0]=A.x; w[1]=A.y; w[2]=A.z; w[3]=A.w;
  w[4]=B.x; w[5]=B.y; w[6]=B.z; w[7]=B.w;
}

// w[0..7] = cc[m0..m0+7], where (m0+HALO) % 4 == 3: three aligned float4 loads.
__device__ __forceinline__ void load8_b(const float4* __restrict__ cc4,
                                        int m0, float* w) {
  const int q = (m0 + HALO - 3) >> 2;   // (m0+HALO-3) % 4 == 0
  const float4 A = cc4[q];              // covers m0-3 .. m0
  const float4 B = cc4[q + 1];          // m0+1 .. m0+4
  const float4 C = cc4[q + 2];          // m0+5 .. m0+8
  w[0]=A.w;
  w[1]=B.x; w[2]=B.y; w[3]=B.z; w[4]=B.w;
  w[5]=C.x; w[6]=C.y; w[7]=C.z;
}

__global__ void __launch_bounds__(LANES)
__attribute__((amdgpu_waves_per_eu(4, 4)))    // pin 4/SIMD: 128-VGPR budget,
bk_kernel(const float* __restrict__ v,        // no incentive to spill R
          const float* __restrict__ hdiag,
          const float* __restrict__ ccf,      // zero-padded couplings (d_ws)
          float2* __restrict__ out,
          int N, int chunks_per_row) {
  #pragma clang fp contract(off)
  __shared__ float sA[SPAD];            // negA only: ~8.7 KB

  const int tid  = threadIdx.x;
  const int row  = blockIdx.x / chunks_per_row;
  const int ch   = blockIdx.x - row * chunks_per_row;
  const int base = ch * CHUNK;
  const long rowoff = (long)row * N;
  const float4* cc4 = (const float4*)ccf;

  // ---- stage negA, coalesced; zeros outside [0,N) --------------------------
  for (int i = tid; i < STAGE; i += LANES) {
    const int k = base - HALO + i;
    float na = 0.0f;
    if (k >= 0 && k < N) na = neg_a(v[rowoff + k], hdiag[k]);
    sA[padi(i)] = na;
  }
  __syncthreads();

  const int s0  = base + tid * SEG;
  const int s1  = s0 + SEG;
  const int li0 = tid * SEG + HALO;     // sA (unpadded) index of s0

  float Rr[SEG], Ri[SEG];               // must stay in VGPRs (128 budget)
  float crB, ciB;                       // backward carry (R)
  float crF, ciF;                       // forward-warmup carry (L)
  float wcB[8], wcF[8];

  // ---- paired warmups (independent chains, interleaved for ILP) -----------
  // bwd: R[k-1] = cc[k-1] / (z - a[k] - R[k]), k = s1+WARM-1 .. s1, carry 0.
  // fwd: L[k+1] = cc[k]   / (z - a[k] - L[k]), k = s0-WARM .. s0-1, carry 0.
  // Zero-padded fake steps (cc=0) are bit-transparent (validated R4+).
  crB = 0.0f; ciB = 0.0f; crF = 0.0f; ciF = 0.0f;
  for (int g = 0; g < WARM / 8; ++g) {
    const int kh = s1 + (WARM - 1) - 8 * g;   // bwd group high k
    const int kl = s0 - WARM + 8 * g;         // fwd group low k
    load8_b(cc4, kh - 8, wcB);                // wcB[j'] = cc[kh-8+j']
    load8_f(cc4, kl, wcF);                    // wcF[j]  = cc[kl+j]
    #pragma unroll
    for (int j = 0; j < 8; ++j) {
      const float naB = sA[padi(kh - j - base + HALO)];
      const float naF = sA[padi(kl + j - base + HALO)];
      cf_step(naB, wcB[7 - j], crB, ciB);     // cc[k-1], k = kh-j
      cf_step(naF, wcF[j],     crF, ciF);     // cc[k],   k = kl+j
    }
  }
  Rr[SEG-1] = crB; Ri[SEG-1] = ciB;           // R[s1-1]

  // ---- backward main: t = SEG-1 .. 1, store R -----------------------------
  #pragma unroll
  for (int tg = 0; tg < SEG / 8; ++tg) {
    const int th = SEG - 1 - 8 * tg;          // high t of this group
    load8_b(cc4, s0 + th - 8, wcB);           // wcB[j'] = cc[s0+th-8+j']
    #pragma unroll
    for (int j = 0; j < 8; ++j) {
      const int t = th - j;
      if (t >= 1) {
        const float na = sA[padi(li0 + t)];
        cf_step(na, wcB[7 - j], crB, ciB);    // cc[k-1], k = s0+t
        Rr[t-1] = crB; Ri[t-1] = ciB;
      }
    }
  }

  // ---- forward main: combine with R, store G, advance L -------------------
  // (combine-npdiv and advance-npdiv are mutually independent: 2-wide ILP)
  #pragma unroll
  for (int tg = 0; tg < SEG / 8; ++tg) {
    const int kl = s0 + 8 * tg;
    load8_f(cc4, kl, wcF);                    // wcF[j] = cc[kl+j]
    #pragma unroll
    for (int j = 0; j < 8; ++j) {
      const int t = 8 * tg + j;
      const float na  = sA[padi(li0 + t)];
      const float drL = na - crF;             // (z - a) - L
      const float diL = 1.0f - ciF;
      const float drf = drL - Rr[t];          // ... - R
      const float dif = diL - Ri[t];
      const C2 G = npdiv(1.0f, drf, dif);
      out[rowoff + kl + j] = make_float2(fq_out(G.r), fq_out(G.i));
      if (t < SEG - 1) {                      // advance L within segment
        const C2 nc = npdiv(wcF[j], drL, diL);
        crF = nc.r; ciF = nc.i;
      }
    }
  }
}

extern "C" void kernel_launch(void* const* d_in, const int* in_sizes, int n_in,
                              void* d_out, int out_size, void* d_ws, size_t ws_size,
                              hipStream_t stream) {
  const float* v    = (const float*)d_in[0];
  const float* hd   = (const float*)d_in[1];
  const float* hsub = (const float*)d_in[2];
  const float* hsup = (const float*)d_in[3];
  const int N = in_sizes[1];
  const int B = in_sizes[0] / N;
  const int chunks = (N + CHUNK - 1) / CHUNK;    // 8 for N=16384 (exact)

  float* ccf = (float*)d_ws;                     // N + 2*HALO + 8 floats
  const int ccn = N + 2*HALO + 8;
  cc_kernel<<<(ccn + 255) / 256, 256, 0, stream>>>(hsub, hsup, ccf, N);
  bk_kernel<<<B * chunks, LANES, 0, stream>>>(v, hd, ccf, (float2*)d_out,
                                              N, chunks);
}

// Round 11
// 132.491 us; speedup vs baseline: 1.1771x; 1.0597x over previous
//
#include <hip/hip_runtime.h>

// QuantizedBKCore: tridiagonal resolvent diagonal via two continued-fraction
// sweeps, bit-exact vs numpy float32/complex64 reference (validated R1-R10:
// absmax == 0 with Smith division, contract(off), rintf, exact op order).
//
// R11: R9/R10 pinned at ~64us: VALUBusy 57%, per-wave duty 23%, grid-capped
// at 4 waves/SIMD — each wave stalls ~77% on its own serial IEEE-div chain.
// Two changes:
//  (1) cheap warmup: first 16 warmup steps use carry=cc*conj(den)*rcp(|den|^2)
//      (v_rcp_f32, ~5-op dep chain vs 2 IEEE-div expansions). Rcp noise
//      ~2 ulp/step contracts (<=0.38/step) to a ~2e-7 tube; an 8-step EXACT
//      Smith tail then contracts to <6e-9 < half-ulp even at the worst
//      transient factor 0.65/step -> bit-merge preserved.
//  (2) SEG 32->16: CHUNK=1024, 8192 blocks = 32/CU = 8 waves/SIMD (2x waves),
//      LDS 4.4KB, R arrays halve. Cheap warmup cancels the doubled warmup
//      overhead: npdiv-equiv/elem ~4.4 == R9.
// Skeleton otherwise identical: negA staged in LDS (stride-33 pad), cc via
// zero-padded d_ws copy + aligned float4 group loads, paired fwd/bwd warmup
// interleave (R9), R spill-to-L2 tolerated (reloads are chain-independent).

#define SEG    16                 // elements per lane
#define WCHEAP 16                 // approximate warmup steps (rcp-based)
#define WEXACT 8                  // exact Smith-tail steps
#define WARM   (WCHEAP + WEXACT)  // 24 total; HALO multiple of 4
#define LANES  64                 // threads per block (1 wave)
#define CHUNK  (LANES*SEG)        // 1024 elements per block
#define HALO   WARM
#define STAGE  (CHUNK + 2*HALO)   // 1072 staged negA values
#define SPAD   (STAGE + STAGE/32 + 1)  // stride-33 padding (2-way only: free)

struct C2 { float r, i; };

__device__ __forceinline__ int padi(int i) { return i + (i >> 5); }

// numpy CFLOAT_divide (Smith), numerator (nr, 0), no FMA contraction.
__device__ __forceinline__ C2 npdiv(float nr, float dr, float di) {
  #pragma clang fp contract(off)
  const bool  b   = fabsf(dr) >= fabsf(di);
  const float num = b ? di : dr;
  const float den = b ? dr : di;
  const float rat = num / den;          // IEEE-correct div
  const float t   = num * rat;
  const float s   = den + t;            // mul + add, NOT fma
  const float scl = 1.0f / s;           // IEEE-correct div
  const float u   = nr * scl;
  const float m   = nr * rat;
  const float w   = m * scl;
  C2 o;
  o.r = b ? u : w;
  o.i = b ? -w : -u;                    // sign-of-product flip is exact
  return o;
}

// exact continued-fraction step: carry <- cv / (z - a - carry), z = i
__device__ __forceinline__ void cf_step(float na, float cv, float& cr, float& ci) {
  #pragma clang fp contract(off)
  const float dr = na - cr;
  const float di = 1.0f - ci;
  const C2 nc = npdiv(cv, dr, di);
  cr = nc.r; ci = nc.i;
}

// cheap approximate step (warmup only, pre-merge): same map via rcp.
// cv=0 halo fakes stay bit-transparent: t=0 -> carry=(+-0,-+0).
__device__ __forceinline__ void cf_cheap(float na, float cv, float& cr, float& ci) {
  const float dr = na - cr;
  const float di = 1.0f - ci;
  const float m2 = dr * dr + di * di;         // in [1, ~130]
  const float r  = __builtin_amdgcn_rcpf(m2); // v_rcp_f32, ~1 ulp
  const float t  = cv * r;
  cr = dr * t;
  ci = -(di * t);
}

// -(clip(h0_diag + fake_quantize(v), -10, 10)); exact op order.
__device__ __forceinline__ float neg_a(float vv, float hd) {
  #pragma clang fp contract(off)
  float q = rintf(vv);                  // round half-even == np.rint
  q = fminf(fmaxf(q, -128.0f), 127.0f);
  float he = hd + q;
  he = fminf(fmaxf(he, -10.0f), 10.0f);
  return 0.0f - he;                     // Re(z - a)
}

// clip(+-100) -> rint -> clip(+-128); exact ops.
__device__ __forceinline__ float fq_out(float x) {
  #pragma clang fp contract(off)
  x = fminf(fmaxf(x, -100.0f), 100.0f);
  x = rintf(x);
  x = fminf(fmaxf(x, -128.0f), 127.0f);
  return x;
}

// ccf[i] = cc[i-HALO] zero-padded: i in [0, N + 2*HALO + 8)
__global__ void cc_kernel(const float* __restrict__ hsub,
                          const float* __restrict__ hsup,
                          float* __restrict__ ccf, int N) {
  #pragma clang fp contract(off)
  const int i = blockIdx.x * blockDim.x + threadIdx.x;
  if (i < N + 2*HALO + 8) {
    const int k = i - HALO;
    ccf[i] = (k >= 0 && k < N - 1) ? hsub[k] * hsup[k] : 0.0f;
  }
}

// w[0..7] = cc[m0..m0+7], where (m0+HALO) % 4 == 0: two aligned float4 loads.
__device__ __forceinline__ void load8_f(const float4* __restrict__ cc4,
                                        int m0, float* w) {
  const int q = (m0 + HALO) >> 2;
  const float4 A = cc4[q];
  const float4 B = cc4[q + 1];
  w[0]=A.x; w[1]=A.y; w[2]=A.z; w[3]=A.w;
  w[4]=B.x; w[5]=B.y; w[6]=B.z; w[7]=B.w;
}

// w[0..7] = cc[m0..m0+7], where (m0+HALO) % 4 == 3: three aligned float4 loads.
__device__ __forceinline__ void load8_b(const float4* __restrict__ cc4,
                                        int m0, float* w) {
  const int q = (m0 + HALO - 3) >> 2;   // (m0+HALO-3) % 4 == 0
  const float4 A = cc4[q];              // covers m0-3 .. m0
  const float4 B = cc4[q + 1];          // m0+1 .. m0+4
  const float4 C = cc4[q + 2];          // m0+5 .. m0+8
  w[0]=A.w;
  w[1]=B.x; w[2]=B.y; w[3]=B.z; w[4]=B.w;
  w[5]=C.x; w[6]=C.y; w[7]=C.z;
}

__global__ void __launch_bounds__(LANES)
bk_kernel(const float* __restrict__ v,
          const float* __restrict__ hdiag,
          const float* __restrict__ ccf,      // zero-padded couplings (d_ws)
          float2* __restrict__ out,
          int N, int chunks_per_row) {
  #pragma clang fp contract(off)
  __shared__ float sA[SPAD];            // negA only: ~4.4 KB

  const int tid  = threadIdx.x;
  const int row  = blockIdx.x / chunks_per_row;
  const int ch   = blockIdx.x - row * chunks_per_row;
  const int base = ch * CHUNK;
  const long rowoff = (long)row * N;
  const float4* cc4 = (const float4*)ccf;

  // ---- stage negA, coalesced; zeros outside [0,N) --------------------------
  for (int i = tid; i < STAGE; i += LANES) {
    const int k = base - HALO + i;
    float na = 0.0f;
    if (k >= 0 && k < N) na = neg_a(v[rowoff + k], hdiag[k]);
    sA[padi(i)] = na;
  }
  __syncthreads();

  const int s0  = base + tid * SEG;
  const int s1  = s0 + SEG;
  const int li0 = tid * SEG + HALO;     // sA (unpadded) index of s0

  float Rr[SEG], Ri[SEG];
  float crB, ciB;                       // backward carry (R)
  float crF, ciF;                       // forward-warmup carry (L)
  float wcB[8], wcF[8];

  // ---- paired warmups (independent chains, interleaved for ILP) -----------
  // bwd: R[k-1] = cc[k-1] / (z - a[k] - R[k]), k = s1+23 .. s1, carry 0.
  // fwd: L[k+1] = cc[k]   / (z - a[k] - L[k]), k = s0-24 .. s0-1, carry 0.
  // Groups g=0,1: cheap rcp steps (pre-merge). g=2: exact Smith tail.
  crB = 0.0f; ciB = 0.0f; crF = 0.0f; ciF = 0.0f;
  #pragma unroll
  for (int g = 0; g < WARM / 8; ++g) {
    const int kh = s1 + (WARM - 1) - 8 * g;   // bwd group high k
    const int kl = s0 - WARM + 8 * g;         // fwd group low k
    load8_b(cc4, kh - 8, wcB);                // wcB[j'] = cc[kh-8+j']
    load8_f(cc4, kl, wcF);                    // wcF[j]  = cc[kl+j]
    #pragma unroll
    for (int j = 0; j < 8; ++j) {
      const float naB = sA[padi(kh - j - base + HALO)];
      const float naF = sA[padi(kl + j - base + HALO)];
      if (g < (WCHEAP / 8)) {                 // cheap phase
        cf_cheap(naB, wcB[7 - j], crB, ciB);  // cc[k-1], k = kh-j
        cf_cheap(naF, wcF[j],     crF, ciF);  // cc[k],   k = kl+j
      } else {                                // exact Smith tail
        cf_step(naB, wcB[7 - j], crB, ciB);
        cf_step(naF, wcF[j],     crF, ciF);
      }
    }
  }
  Rr[SEG-1] = crB; Ri[SEG-1] = ciB;           // R[s1-1]

  // ---- backward main: t = SEG-1 .. 1, store R -----------------------------
  #pragma unroll
  for (int tg = 0; tg < SEG / 8; ++tg) {
    const int th = SEG - 1 - 8 * tg;          // high t of this group
    load8_b(cc4, s0 + th - 8, wcB);           // wcB[j'] = cc[s0+th-8+j']
    #pragma unroll
    for (int j = 0; j < 8; ++j) {
      const int t = th - j;
      if (t >= 1) {
        const float na = sA[padi(li0 + t)];
        cf_step(na, wcB[7 - j], crB, ciB);    // cc[k-1], k = s0+t
        Rr[t-1] = crB; Ri[t-1] = ciB;
      }
    }
  }

  // ---- forward main: combine with R, store G, advance L -------------------
  // (combine-npdiv and advance-npdiv are mutually independent: 2-wide ILP)
  #pragma unroll
  for (int tg = 0; tg < SEG / 8; ++tg) {
    const int kl = s0 + 8 * tg;
    load8_f(cc4, kl, wcF);                    // wcF[j] = cc[kl+j]
    #pragma unroll
    for (int j = 0; j < 8; ++j) {
      const int t = 8 * tg + j;
      const float na  = sA[padi(li0 + t)];
      const float drL = na - crF;             // (z - a) - L
      const float diL = 1.0f - ciF;
      const float drf = drL - Rr[t];          // ... - R
      const float dif = diL - Ri[t];
      const C2 G = npdiv(1.0f, drf, dif);
      out[rowoff + kl + j] = make_float2(fq_out(G.r), fq_out(G.i));
      if (t < SEG - 1) {                      // advance L within segment
        const C2 nc = npdiv(wcF[j], drL, diL);
        crF = nc.r; ciF = nc.i;
      }
    }
  }
}

extern "C" void kernel_launch(void* const* d_in, const int* in_sizes, int n_in,
                              void* d_out, int out_size, void* d_ws, size_t ws_size,
                              hipStream_t stream) {
  const float* v    = (const float*)d_in[0];
  const float* hd   = (const float*)d_in[1];
  const float* hsub = (const float*)d_in[2];
  const float* hsup = (const float*)d_in[3];
  const int N = in_sizes[1];
  const int B = in_sizes[0] / N;
  const int chunks = (N + CHUNK - 1) / CHUNK;    // 16 for N=16384 (exact)

  float* ccf = (float*)d_ws;                     // N + 2*HALO + 8 floats
  const int ccn = N + 2*HALO + 8;
  cc_kernel<<<(ccn + 255) / 256, 256, 0, stream>>>(hsub, hsup, ccf, N);
  bk_kernel<<<B * chunks, LANES, 0, stream>>>(v, hd, ccf, (float2*)d_out,
                                              N, chunks);
}

// Round 12
// 125.087 us; speedup vs baseline: 1.2467x; 1.0592x over previous
//
#include <hip/hip_runtime.h>

// QuantizedBKCore: tridiagonal resolvent diagonal via two continued-fraction
// sweeps, bit-exact vs numpy float32/complex64 reference (validated R1-R11:
// absmax == 0; R11 added rcp-based cheap warmup + exact Smith tail).
//
// R12 = R11 + fdiv_ieee: the exact npdiv divisions are replaced by the bare
// 8-op Newton core of the compiler's own fdiv expansion (rcp, e0, r1, q0,
// e1, q1, e2, fma). For our operand ranges (Smith den in [0.7,26], num<=130,
// results normal) v_div_scale is the identity and v_div_fixup passes the
// quotient through, so this is bit-identical BY CONSTRUCTION to IEEE div
// (= numpy) while dropping ~8 instrs + scale/fixup latency per division,
// 2 divisions per exact step — the dominant issue+latency term at R11's
// VALUBusy=67%. Everything else identical to R11 (SEG=16, cheap warmup 16 +
// exact tail 8, LDS negA staging, float4 cc loads from zero-padded d_ws).

#define SEG    16                 // elements per lane
#define WCHEAP 16                 // approximate warmup steps (rcp-based)
#define WEXACT 8                  // exact Smith-tail steps
#define WARM   (WCHEAP + WEXACT)  // 24 total; HALO multiple of 4
#define LANES  64                 // threads per block (1 wave)
#define CHUNK  (LANES*SEG)        // 1024 elements per block
#define HALO   WARM
#define STAGE  (CHUNK + 2*HALO)   // 1072 staged negA values
#define SPAD   (STAGE + STAGE/32 + 1)  // stride-33 padding (2-way only: free)

struct C2 { float r, i; };

__device__ __forceinline__ int padi(int i) { return i + (i >> 5); }

// IEEE-correctly-rounded f32 divide for mid-range normal operands.
// Exactly the Newton core of LLVM's gfx9 fdiv expansion; div_scale/div_fixup
// are identity for den in [~0.7, 26], num <= 130 (all values arising here),
// so the result is bit-identical to the compiler's a/b (= numpy's divide).
__device__ __forceinline__ float fdiv_ieee(float num, float den) {
  const float r0 = __builtin_amdgcn_rcpf(den);
  const float e0 = __builtin_fmaf(-den, r0, 1.0f);
  const float r1 = __builtin_fmaf(e0, r0, r0);
  const float q0 = num * r1;
  const float e1 = __builtin_fmaf(-den, q0, num);
  const float q1 = __builtin_fmaf(e1, r1, q0);
  const float e2 = __builtin_fmaf(-den, q1, num);
  return __builtin_fmaf(e2, r1, q1);
}

// numpy CFLOAT_divide (Smith), numerator (nr, 0), no FMA contraction in the
// surrounding mul/add ops (explicit fmaf inside fdiv_ieee is intentional).
__device__ __forceinline__ C2 npdiv(float nr, float dr, float di) {
  #pragma clang fp contract(off)
  const bool  b   = fabsf(dr) >= fabsf(di);
  const float num = b ? di : dr;
  const float den = b ? dr : di;
  const float rat = fdiv_ieee(num, den);  // == IEEE num/den (range-proven)
  const float t   = num * rat;
  const float s   = den + t;              // mul + add, NOT fma
  const float scl = fdiv_ieee(1.0f, s);   // == IEEE 1/s
  const float u   = nr * scl;
  const float m   = nr * rat;
  const float w   = m * scl;
  C2 o;
  o.r = b ? u : w;
  o.i = b ? -w : -u;                      // sign-of-product flip is exact
  return o;
}

// exact continued-fraction step: carry <- cv / (z - a - carry), z = i
__device__ __forceinline__ void cf_step(float na, float cv, float& cr, float& ci) {
  #pragma clang fp contract(off)
  const float dr = na - cr;
  const float di = 1.0f - ci;
  const C2 nc = npdiv(cv, dr, di);
  cr = nc.r; ci = nc.i;
}

// cheap approximate step (warmup only, pre-merge): same map via rcp.
// cv=0 halo fakes stay bit-transparent: t=0 -> carry=(+-0,-+0).
__device__ __forceinline__ void cf_cheap(float na, float cv, float& cr, float& ci) {
  const float dr = na - cr;
  const float di = 1.0f - ci;
  const float m2 = dr * dr + di * di;         // in [1, ~130]
  const float r  = __builtin_amdgcn_rcpf(m2); // v_rcp_f32, ~1 ulp
  const float t  = cv * r;
  cr = dr * t;
  ci = -(di * t);
}

// -(clip(h0_diag + fake_quantize(v), -10, 10)); exact op order.
__device__ __forceinline__ float neg_a(float vv, float hd) {
  #pragma clang fp contract(off)
  float q = rintf(vv);                  // round half-even == np.rint
  q = fminf(fmaxf(q, -128.0f), 127.0f);
  float he = hd + q;
  he = fminf(fmaxf(he, -10.0f), 10.0f);
  return 0.0f - he;                     // Re(z - a)
}

// clip(+-100) -> rint -> clip(+-128); exact ops.
__device__ __forceinline__ float fq_out(float x) {
  #pragma clang fp contract(off)
  x = fminf(fmaxf(x, -100.0f), 100.0f);
  x = rintf(x);
  x = fminf(fmaxf(x, -128.0f), 127.0f);
  return x;
}

// ccf[i] = cc[i-HALO] zero-padded: i in [0, N + 2*HALO + 8)
__global__ void cc_kernel(const float* __restrict__ hsub,
                          const float* __restrict__ hsup,
                          float* __restrict__ ccf, int N) {
  #pragma clang fp contract(off)
  const int i = blockIdx.x * blockDim.x + threadIdx.x;
  if (i < N + 2*HALO + 8) {
    const int k = i - HALO;
    ccf[i] = (k >= 0 && k < N - 1) ? hsub[k] * hsup[k] : 0.0f;
  }
}

// w[0..7] = cc[m0..m0+7], where (m0+HALO) % 4 == 0: two aligned float4 loads.
__device__ __forceinline__ void load8_f(const float4* __restrict__ cc4,
                                        int m0, float* w) {
  const int q = (m0 + HALO) >> 2;
  const float4 A = cc4[q];
  const float4 B = cc4[q + 1];
  w[0]=A.x; w[1]=A.y; w[2]=A.z; w[3]=A.w;
  w[4]=B.x; w[5]=B.y; w[6]=B.z; w[7]=B.w;
}

// w[0..7] = cc[m0..m0+7], where (m0+HALO) % 4 == 3: three aligned float4 loads.
__device__ __forceinline__ void load8_b(const float4* __restrict__ cc4,
                                        int m0, float* w) {
  const int q = (m0 + HALO - 3) >> 2;   // (m0+HALO-3) % 4 == 0
  const float4 A = cc4[q];              // covers m0-3 .. m0
  const float4 B = cc4[q + 1];          // m0+1 .. m0+4
  const float4 C = cc4[q + 2];          // m0+5 .. m0+8
  w[0]=A.w;
  w[1]=B.x; w[2]=B.y; w[3]=B.z; w[4]=B.w;
  w[5]=C.x; w[6]=C.y; w[7]=C.z;
}

__global__ void __launch_bounds__(LANES)
bk_kernel(const float* __restrict__ v,
          const float* __restrict__ hdiag,
          const float* __restrict__ ccf,      // zero-padded couplings (d_ws)
          float2* __restrict__ out,
          int N, int chunks_per_row) {
  #pragma clang fp contract(off)
  __shared__ float sA[SPAD];            // negA only: ~4.4 KB

  const int tid  = threadIdx.x;
  const int row  = blockIdx.x / chunks_per_row;
  const int ch   = blockIdx.x - row * chunks_per_row;
  const int base = ch * CHUNK;
  const long rowoff = (long)row * N;
  const float4* cc4 = (const float4*)ccf;

  // ---- stage negA, coalesced; zeros outside [0,N) --------------------------
  for (int i = tid; i < STAGE; i += LANES) {
    const int k = base - HALO + i;
    float na = 0.0f;
    if (k >= 0 && k < N) na = neg_a(v[rowoff + k], hdiag[k]);
    sA[padi(i)] = na;
  }
  __syncthreads();

  const int s0  = base + tid * SEG;
  const int s1  = s0 + SEG;
  const int li0 = tid * SEG + HALO;     // sA (unpadded) index of s0

  float Rr[SEG], Ri[SEG];
  float crB, ciB;                       // backward carry (R)
  float crF, ciF;                       // forward-warmup carry (L)
  float wcB[8], wcF[8];

  // ---- paired warmups (independent chains, interleaved for ILP) -----------
  // bwd: R[k-1] = cc[k-1] / (z - a[k] - R[k]), k = s1+23 .. s1, carry 0.
  // fwd: L[k+1] = cc[k]   / (z - a[k] - L[k]), k = s0-24 .. s0-1, carry 0.
  // Groups g=0,1: cheap rcp steps (pre-merge). g=2: exact Smith tail.
  crB = 0.0f; ciB = 0.0f; crF = 0.0f; ciF = 0.0f;
  #pragma unroll
  for (int g = 0; g < WARM / 8; ++g) {
    const int kh = s1 + (WARM - 1) - 8 * g;   // bwd group high k
    const int kl = s0 - WARM + 8 * g;         // fwd group low k
    load8_b(cc4, kh - 8, wcB);                // wcB[j'] = cc[kh-8+j']
    load8_f(cc4, kl, wcF);                    // wcF[j]  = cc[kl+j]
    #pragma unroll
    for (int j = 0; j < 8; ++j) {
      const float naB = sA[padi(kh - j - base + HALO)];
      const float naF = sA[padi(kl + j - base + HALO)];
      if (g < (WCHEAP / 8)) {                 // cheap phase
        cf_cheap(naB, wcB[7 - j], crB, ciB);  // cc[k-1], k = kh-j
        cf_cheap(naF, wcF[j],     crF, ciF);  // cc[k],   k = kl+j
      } else {                                // exact Smith tail
        cf_step(naB, wcB[7 - j], crB, ciB);
        cf_step(naF, wcF[j],     crF, ciF);
      }
    }
  }
  Rr[SEG-1] = crB; Ri[SEG-1] = ciB;           // R[s1-1]

  // ---- backward main: t = SEG-1 .. 1, store R -----------------------------
  #pragma unroll
  for (int tg = 0; tg < SEG / 8; ++tg) {
    const int th = SEG - 1 - 8 * tg;          // high t of this group
    load8_b(cc4, s0 + th - 8, wcB);           // wcB[j'] = cc[s0+th-8+j']
    #pragma unroll
    for (int j = 0; j < 8; ++j) {
      const int t = th - j;
      if (t >= 1) {
        const float na = sA[padi(li0 + t)];
        cf_step(na, wcB[7 - j], crB, ciB);    // cc[k-1], k = s0+t
        Rr[t-1] = crB; Ri[t-1] = ciB;
      }
    }
  }

  // ---- forward main: combine with R, store G, advance L -------------------
  // (combine-npdiv and advance-npdiv are mutually independent: 2-wide ILP)
  #pragma unroll
  for (int tg = 0; tg < SEG / 8; ++tg) {
    const int kl = s0 + 8 * tg;
    load8_f(cc4, kl, wcF);                    // wcF[j] = cc[kl+j]
    #pragma unroll
    for (int j = 0; j < 8; ++j) {
      const int t = 8 * tg + j;
      const float na  = sA[padi(li0 + t)];
      const float drL = na - crF;             // (z - a) - L
      const float diL = 1.0f - ciF;
      const float drf = drL - Rr[t];          // ... - R
      const float dif = diL - Ri[t];
      const C2 G = npdiv(1.0f, drf, dif);
      out[rowoff + kl + j] = make_float2(fq_out(G.r), fq_out(G.i));
      if (t < SEG - 1) {                      // advance L within segment
        const C2 nc = npdiv(wcF[j], drL, diL);
        crF = nc.r; ciF = nc.i;
      }
    }
  }
}

extern "C" void kernel_launch(void* const* d_in, const int* in_sizes, int n_in,
                              void* d_out, int out_size, void* d_ws, size_t ws_size,
                              hipStream_t stream) {
  const float* v    = (const float*)d_in[0];
  const float* hd   = (const float*)d_in[1];
  const float* hsub = (const float*)d_in[2];
  const float* hsup = (const float*)d_in[3];
  const int N = in_sizes[1];
  const int B = in_sizes[0] / N;
  const int chunks = (N + CHUNK - 1) / CHUNK;    // 16 for N=16384 (exact)

  float* ccf = (float*)d_ws;                     // N + 2*HALO + 8 floats
  const int ccn = N + 2*HALO + 8;
  cc_kernel<<<(ccn + 255) / 256, 256, 0, stream>>>(hsub, hsup, ccf, N);
  bk_kernel<<<B * chunks, LANES, 0, stream>>>(v, hd, ccf, (float2*)d_out,
                                              N, chunks);
}